// Round 14
// baseline (711.371 us; speedup 1.0000x reference)
//
#include <hip/hip_runtime.h>
#include <math.h>

#define NN 4096
#define DM 256

enum { ACT_NONE = 0, ACT_RELU = 1, ACT_TANH = 2 };

typedef __attribute__((ext_vector_type(8))) short short8v;
typedef __attribute__((ext_vector_type(16))) float f32x16;

__device__ __forceinline__ unsigned short f2bf(float f) {
  unsigned int u = __float_as_uint(f);
  unsigned int r = (u + 0x7FFFu + ((u >> 16) & 1u)) >> 16;
  return (unsigned short)r;
}
__device__ __forceinline__ float bf2f(unsigned short u) {
  return __uint_as_float(((unsigned int)u) << 16);
}

// ---------------- batched weight prep ---------------------------------------
struct CastJob { const float* s; unsigned short* d; int n4; };
__global__ __launch_bounds__(256) void castall_k(CastJob j0, CastJob j1, CastJob j2) {
  const CastJob* jp = (blockIdx.y == 0) ? &j0 : (blockIdx.y == 1) ? &j1 : &j2;
  const int i = blockIdx.x * 256 + threadIdx.x;
  if (i < jp->n4) {
    const float4 v = ((const float4*)jp->s)[i];
    ushort4 u;
    u.x = f2bf(v.x); u.y = f2bf(v.y); u.z = f2bf(v.z); u.w = f2bf(v.w);
    ((ushort4*)jp->d)[i] = u;
  }
}

struct TJob { const float* s; unsigned short* d; int K; int N; };
struct TJobs { TJob j[11]; };
// src f32 [K][N] -> dst bf16 [N][K]
__global__ __launch_bounds__(256) void tcastall_k(TJobs js) {
  const TJob jb = js.j[blockIdx.z];
  const int n0 = blockIdx.x * 32, k0 = blockIdx.y * 32;
  if (n0 >= jb.N || k0 >= jb.K) return;
  __shared__ float tile[32][33];
  const int tx = threadIdx.x & 31, ty = threadIdx.x >> 5;
#pragma unroll
  for (int r2 = 0; r2 < 4; r2++)
    tile[ty + r2 * 8][tx] = jb.s[(size_t)(k0 + ty + r2 * 8) * jb.N + n0 + tx];
  __syncthreads();
#pragma unroll
  for (int r2 = 0; r2 < 4; r2++)
    jb.d[(size_t)(n0 + ty + r2 * 8) * jb.K + k0 + tx] = f2bf(tile[tx][ty + r2 * 8]);
}

// ---------------- window -> split ext layout [Wh, Wl, Wh] (K=768) -----------
__global__ __launch_bounds__(256) void wsplit_k(
    const float* __restrict__ w, unsigned short* __restrict__ Awin) {
  const int n = blockIdx.x, t = threadIdx.x;
  const float v = w[(size_t)n * DM + t];
  const unsigned short hi = f2bf(v);
  const unsigned short lo = f2bf(v - bf2f(hi));
  unsigned short* ar = Awin + (size_t)n * 768;
  ar[t] = hi; ar[256 + t] = lo; ar[512 + t] = hi;
}

// ---------------- gl_w [K=256][D=256] -> BglExt[d][768] = [Gh, Gh, Gl] ------
__global__ __launch_bounds__(256) void gsplit_k(
    const float* __restrict__ g, unsigned short* __restrict__ Bgl) {
  __shared__ float tile[32][33];
  const int d0 = blockIdx.x * 32, k0 = blockIdx.y * 32;
  const int tx = threadIdx.x & 31, ty = threadIdx.x >> 5;
#pragma unroll
  for (int r2 = 0; r2 < 4; r2++)
    tile[ty + r2 * 8][tx] = g[(size_t)(k0 + ty + r2 * 8) * DM + d0 + tx];
  __syncthreads();
#pragma unroll
  for (int r2 = 0; r2 < 4; r2++) {
    const int d = d0 + ty + r2 * 8, k = k0 + tx;
    const float v = tile[tx][ty + r2 * 8];
    const unsigned short hi = f2bf(v);
    const unsigned short lo = f2bf(v - bf2f(hi));
    unsigned short* br = Bgl + (size_t)d * 768;
    br[k] = hi; br[256 + k] = hi; br[512 + k] = lo;
  }
}

// ---------------- bf16 MFMA GEMM: C = act(A@Bt^T (+bias) (+res)) ------------
// Staging via global_load_lds width=16: LDS dest linear, XOR swizzle applied
// on the GLOBAL source address; ds_read side reads chunk c at c^(r&7).
template<int ACT, bool BIAS, bool RES, bool F32OUT, bool B16OUT>
__global__ __launch_bounds__(256) void mgemm_k(
    const unsigned short* __restrict__ A, const unsigned short* __restrict__ Bt,
    const float* __restrict__ bias, const float* __restrict__ res,
    float* __restrict__ C, unsigned short* __restrict__ Cb,
    int M, int N, int K) {
  __shared__ short As[64][64];
  __shared__ short Bs[64][64];
  const int t = threadIdx.x;
  const int m0 = blockIdx.y * 64, n0 = blockIdx.x * 64;
  const int wid = t >> 6, l = t & 63, l31 = l & 31, g = l >> 5;
  const int wm = wid >> 1, wn = wid & 1;
  f32x16 acc;
#pragma unroll
  for (int r = 0; r < 16; r++) acc[r] = 0.f;

  const int r0 = wid * 16;
  const int lrow = l >> 3;
  const int pos = l & 7;
  const int swz = (pos ^ lrow) << 3;

  for (int k0 = 0; k0 < K; k0 += 64) {
#pragma unroll
    for (int j = 0; j < 2; j++) {
      const int row = r0 + j * 8 + lrow;
      const short* ga = (const short*)A + (size_t)(m0 + row) * K + k0 + swz;
      const short* gb = (const short*)Bt + (size_t)(n0 + row) * K + k0 + swz;
      __builtin_amdgcn_global_load_lds(
          (const __attribute__((address_space(1))) unsigned int*)ga,
          (__attribute__((address_space(3))) unsigned int*)&As[r0 + j * 8][0],
          16, 0, 0);
      __builtin_amdgcn_global_load_lds(
          (const __attribute__((address_space(1))) unsigned int*)gb,
          (__attribute__((address_space(3))) unsigned int*)&Bs[r0 + j * 8][0],
          16, 0, 0);
    }
    __syncthreads();
#pragma unroll
    for (int ck = 0; ck < 4; ck++) {
      const int c = ck * 2 + g;
      const short8v af = *(const short8v*)&As[wm * 32 + l31][(c ^ (l31 & 7)) * 8];
      const short8v bf = *(const short8v*)&Bs[wn * 32 + l31][(c ^ (l31 & 7)) * 8];
      acc = __builtin_amdgcn_mfma_f32_32x32x16_bf16(bf, af, acc, 0, 0, 0);
    }
    __syncthreads();
  }
  const int m = m0 + wm * 32 + l31;
#pragma unroll
  for (int b = 0; b < 4; b++) {
    const int n = n0 + wn * 32 + b * 8 + g * 4;
    float4 v = make_float4(acc[b * 4 + 0], acc[b * 4 + 1],
                           acc[b * 4 + 2], acc[b * 4 + 3]);
    if (BIAS) {
      v.x += bias[n + 0]; v.y += bias[n + 1];
      v.z += bias[n + 2]; v.w += bias[n + 3];
    }
    if (RES) {
      const float4 rv = *(const float4*)(res + (size_t)m * N + n);
      v.x += rv.x; v.y += rv.y; v.z += rv.z; v.w += rv.w;
    }
    if (ACT == ACT_RELU) {
      v.x = fmaxf(v.x, 0.f); v.y = fmaxf(v.y, 0.f);
      v.z = fmaxf(v.z, 0.f); v.w = fmaxf(v.w, 0.f);
    }
    if (F32OUT) *(float4*)(C + (size_t)m * N + n) = v;
    if (B16OUT) {
      ushort4 uv;
      uv.x = f2bf(v.x); uv.y = f2bf(v.y); uv.z = f2bf(v.z); uv.w = f2bf(v.w);
      *(ushort4*)(Cb + (size_t)m * N + n) = uv;
    }
  }
}

// ---------------- mgemm + tanh + hi/lo split epilogue (h_gl fused) ----------
// C = tanh(A@Bt^T + bias); writes sim Aext [Hi,Lo,Hi] and Bext [Hi,Hi,Lo].
__global__ __launch_bounds__(256) void mgemm_ts_k(
    const unsigned short* __restrict__ A, const unsigned short* __restrict__ Bt,
    const float* __restrict__ bias, unsigned short* __restrict__ Aext,
    unsigned short* __restrict__ Bext, int M, int N, int K) {
  __shared__ short As[64][64];
  __shared__ short Bs[64][64];
  const int t = threadIdx.x;
  const int m0 = blockIdx.y * 64, n0 = blockIdx.x * 64;
  const int wid = t >> 6, l = t & 63, l31 = l & 31, g = l >> 5;
  const int wm = wid >> 1, wn = wid & 1;
  f32x16 acc;
#pragma unroll
  for (int r = 0; r < 16; r++) acc[r] = 0.f;

  const int r0 = wid * 16;
  const int lrow = l >> 3;
  const int pos = l & 7;
  const int swz = (pos ^ lrow) << 3;

  for (int k0 = 0; k0 < K; k0 += 64) {
#pragma unroll
    for (int j = 0; j < 2; j++) {
      const int row = r0 + j * 8 + lrow;
      const short* ga = (const short*)A + (size_t)(m0 + row) * K + k0 + swz;
      const short* gb = (const short*)Bt + (size_t)(n0 + row) * K + k0 + swz;
      __builtin_amdgcn_global_load_lds(
          (const __attribute__((address_space(1))) unsigned int*)ga,
          (__attribute__((address_space(3))) unsigned int*)&As[r0 + j * 8][0],
          16, 0, 0);
      __builtin_amdgcn_global_load_lds(
          (const __attribute__((address_space(1))) unsigned int*)gb,
          (__attribute__((address_space(3))) unsigned int*)&Bs[r0 + j * 8][0],
          16, 0, 0);
    }
    __syncthreads();
#pragma unroll
    for (int ck = 0; ck < 4; ck++) {
      const int c = ck * 2 + g;
      const short8v af = *(const short8v*)&As[wm * 32 + l31][(c ^ (l31 & 7)) * 8];
      const short8v bf = *(const short8v*)&Bs[wn * 32 + l31][(c ^ (l31 & 7)) * 8];
      acc = __builtin_amdgcn_mfma_f32_32x32x16_bf16(bf, af, acc, 0, 0, 0);
    }
    __syncthreads();
  }
  const int m = m0 + wm * 32 + l31;
  unsigned short* ar = Aext + (size_t)m * 768;
  unsigned short* br = Bext + (size_t)m * 768;
#pragma unroll
  for (int b = 0; b < 4; b++) {
    const int n = n0 + wn * 32 + b * 8 + g * 4;
    ushort4 hi4, lo4;
#pragma unroll
    for (int e = 0; e < 4; e++) {
      float v = acc[b * 4 + e] + bias[n + e];
      v = tanhf(v);
      const unsigned short hi = f2bf(v);
      const unsigned short lo = f2bf(v - bf2f(hi));
      ((unsigned short*)&hi4)[e] = hi;
      ((unsigned short*)&lo4)[e] = lo;
    }
    *(ushort4*)(ar + n) = hi4;
    *(ushort4*)(ar + 256 + n) = lo4;
    *(ushort4*)(ar + 512 + n) = hi4;
    *(ushort4*)(br + n) = hi4;
    *(ushort4*)(br + 256 + n) = hi4;
    *(ushort4*)(br + 512 + n) = lo4;
  }
}

// ---------------- 64x128-tile bf16 MFMA GEMM (sim; f32 out, no epilogue) ----
__global__ __launch_bounds__(256) void mgemm2_k(
    const unsigned short* __restrict__ A, const unsigned short* __restrict__ Bt,
    float* __restrict__ C, int M, int N, int K) {
  __shared__ short As[64][64];
  __shared__ short Bs[128][64];
  const int t = threadIdx.x;
  const int m0 = blockIdx.y * 64, n0 = blockIdx.x * 128;
  const int wid = t >> 6, l = t & 63, l31 = l & 31, g = l >> 5;
  const int wm = wid >> 1, wn = wid & 1;
  f32x16 acc0, acc1;
#pragma unroll
  for (int r = 0; r < 16; r++) { acc0[r] = 0.f; acc1[r] = 0.f; }

  const int lrow = l >> 3;
  const int pos = l & 7;
  const int swz = (pos ^ lrow) << 3;

  for (int k0 = 0; k0 < K; k0 += 64) {
#pragma unroll
    for (int j = 0; j < 2; j++) {         // A: wave stages 16 rows
      const int row = wid * 16 + j * 8 + lrow;
      const short* ga = (const short*)A + (size_t)(m0 + row) * K + k0 + swz;
      __builtin_amdgcn_global_load_lds(
          (const __attribute__((address_space(1))) unsigned int*)ga,
          (__attribute__((address_space(3))) unsigned int*)&As[wid * 16 + j * 8][0],
          16, 0, 0);
    }
#pragma unroll
    for (int j = 0; j < 4; j++) {         // B: wave stages 32 rows
      const int row = wid * 32 + j * 8 + lrow;
      const short* gb = (const short*)Bt + (size_t)(n0 + row) * K + k0 + swz;
      __builtin_amdgcn_global_load_lds(
          (const __attribute__((address_space(1))) unsigned int*)gb,
          (__attribute__((address_space(3))) unsigned int*)&Bs[wid * 32 + j * 8][0],
          16, 0, 0);
    }
    __syncthreads();
#pragma unroll
    for (int ck = 0; ck < 4; ck++) {
      const int c = ck * 2 + g;
      const short8v af = *(const short8v*)&As[wm * 32 + l31][(c ^ (l31 & 7)) * 8];
      const short8v bf0 = *(const short8v*)&Bs[wn * 64 + l31][(c ^ (l31 & 7)) * 8];
      const short8v bf1 = *(const short8v*)&Bs[wn * 64 + 32 + l31][(c ^ (l31 & 7)) * 8];
      acc0 = __builtin_amdgcn_mfma_f32_32x32x16_bf16(bf0, af, acc0, 0, 0, 0);
      acc1 = __builtin_amdgcn_mfma_f32_32x32x16_bf16(bf1, af, acc1, 0, 0, 0);
    }
    __syncthreads();
  }
  const int m = m0 + wm * 32 + l31;
#pragma unroll
  for (int b = 0; b < 4; b++) {
    const int n = n0 + wn * 64 + b * 8 + g * 4;
    *(float4*)(C + (size_t)m * N + n) =
        make_float4(acc0[b * 4 + 0], acc0[b * 4 + 1], acc0[b * 4 + 2], acc0[b * 4 + 3]);
    *(float4*)(C + (size_t)m * N + n + 32) =
        make_float4(acc1[b * 4 + 0], acc1[b * 4 + 1], acc1[b * 4 + 2], acc1[b * 4 + 3]);
  }
}

// ---------------- top-16: per-wave reg top16 + single-barrier merge ---------
__global__ __launch_bounds__(256) void topk16_k(
    const float* __restrict__ sim, int* __restrict__ idxo, int rowbase) {
  const int r = blockIdx.x, t = threadIdx.x;
  const int grow = rowbase + r;
  float val[16];
#pragma unroll
  for (int q = 0; q < 16; q++) {
    const int jj = q * 256 + t;
    float v = sim[(size_t)r * NN + jj];
    v = fmaxf(v, 0.f);
    if (jj == grow) v = -1.f;
    val[q] = v;
  }
  __shared__ float cv[64];
  __shared__ int cjs[64];
  const int wave = t >> 6, lane = t & 63;
  float myv = -3.f; int myj = 0;
  for (int it = 0; it < 16; it++) {
    float bv = -10.f; int bj = 0;
#pragma unroll
    for (int q = 0; q < 16; q++)
      if (val[q] > bv) { bv = val[q]; bj = q * 256 + t; }
#pragma unroll
    for (int off = 1; off < 64; off <<= 1) {
      const float ov = __shfl_xor(bv, off);
      const int oj = __shfl_xor(bj, off);
      if (ov > bv || (ov == bv && oj < bj)) { bv = ov; bj = oj; }
    }
    if (lane == it) { myv = bv; myj = bj; }
    if ((bj & 255) == t) {
      const int q = bj >> 8;
#pragma unroll
      for (int qq = 0; qq < 16; qq++) if (qq == q) val[qq] = -2.f;
    }
  }
  if (lane < 16) { cv[wave * 16 + lane] = myv; cjs[wave * 16 + lane] = myj; }
  __syncthreads();
  if (wave == 0) {
    float bv2 = cv[lane]; int bj2 = cjs[lane];
    for (int it = 0; it < 16; it++) {
      float wv = bv2; int wj = bj2;
#pragma unroll
      for (int off = 1; off < 64; off <<= 1) {
        const float ov = __shfl_xor(wv, off);
        const int oj = __shfl_xor(wj, off);
        if (ov > wv || (ov == wv && oj < wj)) { wv = ov; wj = oj; }
      }
      if (lane == 0) idxo[(size_t)grow * 16 + it] = wj;
      if (wj == bj2) bv2 = -3.f;
    }
  }
}

// ---------------- GAT: per-node attention-source/dest scalars ---------------
template<int H>
__global__ __launch_bounds__(256) void gat_prep_k(
    const float* __restrict__ h, const float* __restrict__ as,
    const float* __restrict__ ad, float* __restrict__ es, float* __restrict__ ed) {
  __shared__ float bs[4], bd[4];
  const int n = blockIdx.x, t = threadIdx.x;
  const float v = h[(size_t)n * DM + t];
  float ps = v * as[t];
  float pd = v * ad[t];
#pragma unroll
  for (int off = 32; off >= 1; off >>= 1) {
    ps += __shfl_down(ps, off, 64);
    pd += __shfl_down(pd, off, 64);
  }
  const int wave = t >> 6, lane = t & 63;
  if (H == 4) {
    if (lane == 0) { es[n * 4 + wave] = ps; ed[n * 4 + wave] = pd; }
  } else {
    if (lane == 0) { bs[wave] = ps; bd[wave] = pd; }
    __syncthreads();
    if (t == 0) {
      es[n] = bs[0] + bs[1] + bs[2] + bs[3];
      ed[n] = bd[0] + bd[1] + bd[2] + bd[3];
    }
  }
}

// ---------------- GAT: aggregate 17 in-edges --------------------------------
template<int H, bool RELU, bool B16OUT>
__global__ __launch_bounds__(256) void gat_aggr_k(
    const float* __restrict__ h, const float* __restrict__ es,
    const float* __restrict__ ed, const int* __restrict__ idx,
    const float* __restrict__ bias, float* __restrict__ out,
    unsigned short* __restrict__ outb) {
  const int j = blockIdx.x, t = threadIdx.x;
  const int hd = (H == 4) ? (t >> 6) : 0;
  __shared__ int srcs[17];
  if (t < 16) srcs[t] = idx[(size_t)j * 16 + t];
  if (t == 16) srcs[16] = j;
  __syncthreads();
  const float edj = ed[j * H + hd];
  float e[17]; float m = -1e30f;
#pragma unroll
  for (int k = 0; k < 17; k++) {
    float ev = es[srcs[k] * H + hd] + edj;
    ev = (ev >= 0.f) ? ev : 0.2f * ev;
    e[k] = ev; m = fmaxf(m, ev);
  }
  float s = 0.f;
#pragma unroll
  for (int k = 0; k < 17; k++) { e[k] = expf(e[k] - m); s += e[k]; }
  const float inv = 1.f / s;
  float acc = 0.f;
#pragma unroll
  for (int k = 0; k < 17; k++) acc += e[k] * h[(size_t)srcs[k] * DM + t];
  acc = acc * inv + bias[t];
  if (RELU) acc = fmaxf(acc, 0.f);
  out[(size_t)j * DM + t] = acc;
  if (B16OUT) outb[(size_t)j * DM + t] = f2bf(acc);
}

// ---------------- K/V fragment packer ---------------------------------------
__global__ __launch_bounds__(256) void kvfrag_k(
    const short* __restrict__ qkvs, short* __restrict__ kf,
    short* __restrict__ vf) {
  const int kc = blockIdx.x;   // 32-key chunk
  const int h = blockIdx.y;
  const int t = threadIdx.x;
  __shared__ short Ks[32][72];
  __shared__ short Vs[32][72];
  {
    const int row = t >> 3, ch = t & 7;
    const short* kp = qkvs + (size_t)(kc * 32 + row) * 768 + 256 + h * 64 + ch * 8;
    *(short8v*)&Ks[row][ch * 8] = *(const short8v*)kp;
    const short* vp = qkvs + (size_t)(kc * 32 + row) * 768 + 512 + h * 64 + ch * 8;
    *(short8v*)&Vs[row][ch * 8] = *(const short8v*)vp;
  }
  __syncthreads();
  {
    const int dc = t >> 6, l = t & 63, l31 = l & 31, g = l >> 5;
    short8v kv;
#pragma unroll
    for (int e = 0; e < 8; e++) kv[e] = Ks[l31][dc * 16 + g * 8 + e];
    *(short8v*)(kf + ((size_t)(h * 128 + kc) * 4 + dc) * 512 + l * 8) = kv;
  }
  {
    const int db = t >> 7, kg = (t >> 6) & 1, l = t & 63, l31 = l & 31, g = l >> 5;
    short8v vv;
#pragma unroll
    for (int e = 0; e < 8; e++) {
      const int j = kg * 16 + g * 8 + e;
      const int jp = (j & 19) | ((j & 4) << 1) | ((j & 8) >> 1);
      vv[e] = Vs[jp][db * 32 + l31];
    }
    *(short8v*)(vf + (((size_t)(h * 128 + kc) * 2 + db) * 2 + kg) * 512 + l * 8) = vv;
  }
}

// ---------------- bf16 MFMA flash attention: fragment-coalesced, z=4 --------
// 4 INDEPENDENT waves per 256-thread block (different q-tiles, no barriers).
#define LOADKV(KF, VF, KC) do {                                               \
    const short* kp_ = kfrag + ((size_t)(KC)) * 2048 + l * 8;                 \
    KF##0 = *(const short8v*)(kp_);                                           \
    KF##1 = *(const short8v*)(kp_ + 512);                                     \
    KF##2 = *(const short8v*)(kp_ + 1024);                                    \
    KF##3 = *(const short8v*)(kp_ + 1536);                                    \
    const short* vp_ = vfrag + ((size_t)(KC)) * 2048 + l * 8;                 \
    VF##0 = *(const short8v*)(vp_);                                           \
    VF##1 = *(const short8v*)(vp_ + 512);                                     \
    VF##2 = *(const short8v*)(vp_ + 1024);                                    \
    VF##3 = *(const short8v*)(vp_ + 1536);                                    \
  } while (0)

#define PROCESS(KF, VF) do {                                                  \
    f32x16 accS;                                                              \
    _Pragma("unroll") for (int r = 0; r < 16; r++) accS[r] = 0.f;             \
    __builtin_amdgcn_s_setprio(1);                                            \
    accS = __builtin_amdgcn_mfma_f32_32x32x16_bf16(KF##0, qf[0], accS, 0, 0, 0); \
    accS = __builtin_amdgcn_mfma_f32_32x32x16_bf16(KF##1, qf[1], accS, 0, 0, 0); \
    accS = __builtin_amdgcn_mfma_f32_32x32x16_bf16(KF##2, qf[2], accS, 0, 0, 0); \
    accS = __builtin_amdgcn_mfma_f32_32x32x16_bf16(KF##3, qf[3], accS, 0, 0, 0); \
    __builtin_amdgcn_s_setprio(0);                                            \
    float mt = -1e30f;                                                        \
    _Pragma("unroll") for (int r = 0; r < 16; r++) mt = fmaxf(mt, accS[r]);   \
    mt = fmaxf(mt, __shfl_xor(mt, 32));                                       \
    float pv[16]; float ls = 0.f;                                             \
    if (__all(mt <= mrun + 11.5416f)) {                                       \
      _Pragma("unroll") for (int r = 0; r < 16; r++) {                        \
        pv[r] = exp2f(accS[r] - mrun); ls += pv[r];                           \
      }                                                                       \
      ls += __shfl_xor(ls, 32); lrun += ls;                                   \
    } else {                                                                  \
      const float mnew = fmaxf(mrun, mt);                                     \
      const float corr = exp2f(mrun - mnew);                                  \
      _Pragma("unroll") for (int r = 0; r < 16; r++) {                        \
        pv[r] = exp2f(accS[r] - mnew); ls += pv[r];                           \
      }                                                                       \
      ls += __shfl_xor(ls, 32);                                               \
      lrun = lrun * corr + ls; mrun = mnew;                                   \
      _Pragma("unroll") for (int r = 0; r < 16; r++) {                        \
        accO[0][r] *= corr; accO[1][r] *= corr;                               \
      }                                                                       \
    }                                                                         \
    union { unsigned int u[8]; short8v s[2]; } pf;                            \
    _Pragma("unroll") for (int r = 0; r < 8; r++) {                           \
      unsigned int po;                                                        \
      asm("v_cvt_pk_bf16_f32 %0, %1, %2"                                      \
          : "=v"(po) : "v"(pv[2 * r]), "v"(pv[2 * r + 1]));                   \
      pf.u[r] = po;                                                           \
    }                                                                         \
    __builtin_amdgcn_s_setprio(1);                                            \
    accO[0] = __builtin_amdgcn_mfma_f32_32x32x16_bf16(VF##0, pf.s[0], accO[0], 0, 0, 0); \
    accO[0] = __builtin_amdgcn_mfma_f32_32x32x16_bf16(VF##1, pf.s[1], accO[0], 0, 0, 0); \
    accO[1] = __builtin_amdgcn_mfma_f32_32x32x16_bf16(VF##2, pf.s[0], accO[1], 0, 0, 0); \
    accO[1] = __builtin_amdgcn_mfma_f32_32x32x16_bf16(VF##3, pf.s[1], accO[1], 0, 0, 0); \
    __builtin_amdgcn_s_setprio(0);                                            \
  } while (0)

// grid (32 qgroups, 4 heads, 4 z), block = 256 (4 independent waves).
__global__ __launch_bounds__(256) void attn_flash_k(
    const short* __restrict__ qkvs, const short* __restrict__ kfb,
    const short* __restrict__ vfb, unsigned short* __restrict__ opart,
    float* __restrict__ ml) {
  const int t = threadIdx.x;
  const int wv = t >> 6;
  const int l = t & 63;
  const int qb = (blockIdx.x * 4 + wv) * 32;
  const int h = blockIdx.y;
  const int z = blockIdx.z;
  const int l31 = l & 31, g = l >> 5;

  short8v qf[4];
  {
    const short* qp = qkvs + (size_t)(qb + l31) * 768 + h * 64 + g * 8;
#pragma unroll
    for (int c = 0; c < 4; c++) {
      short8v qv = *(const short8v*)(qp + c * 16);
#pragma unroll
      for (int e = 0; e < 8; e++)
        qv[e] = (short)f2bf(bf2f((unsigned short)qv[e]) * 0.18033688f);
      qf[c] = qv;
    }
  }

  f32x16 accO[2];
#pragma unroll
  for (int r = 0; r < 16; r++) { accO[0][r] = 0.f; accO[1][r] = 0.f; }
  float mrun = -1e30f, lrun = 0.f;

  const short* kfrag = kfb + (size_t)h * 128 * 2048;
  const short* vfrag = vfb + (size_t)h * 128 * 2048;
  const int kc0 = z * 32;

  short8v kA0, kA1, kA2, kA3, vA0, vA1, vA2, vA3;
  short8v kB0, kB1, kB2, kB3, vB0, vB1, vB2, vB3;
  LOADKV(kA, vA, kc0);
  for (int it = 0; it < 16; it++) {
    LOADKV(kB, vB, kc0 + (it * 2 + 1));
    PROCESS(kA, vA);
    LOADKV(kA, vA, kc0 + ((it * 2 + 2) & 31));  // wraps on last iter
    PROCESS(kB, vB);
  }

  const int q = qb + l31;
  unsigned short* op = opart + ((size_t)z * NN + q) * DM + h * 64;
#pragma unroll
  for (int db = 0; db < 2; db++) {
#pragma unroll
    for (int rq = 0; rq < 4; rq++) {
      ushort4 v4;
      v4.x = f2bf(accO[db][rq * 4 + 0]);
      v4.y = f2bf(accO[db][rq * 4 + 1]);
      v4.z = f2bf(accO[db][rq * 4 + 2]);
      v4.w = f2bf(accO[db][rq * 4 + 3]);
      *(ushort4*)(op + db * 32 + rq * 8 + g * 4) = v4;
    }
  }
  if (g == 0) {
    ml[(((size_t)z * 4 + h) * NN + q) * 2 + 0] = mrun;   // log2-domain
    ml[(((size_t)z * 4 + h) * NN + q) * 2 + 1] = lrun;
  }
}

// ---------------- merge 4 flash partials (m in log2 domain) -----------------
__global__ __launch_bounds__(256) void attn_merge_k(
    const unsigned short* __restrict__ opart, const float* __restrict__ ml,
    unsigned short* __restrict__ ob) {
  const int q = blockIdx.x;
  const int t = threadIdx.x;
  const int h = t >> 6;
  float m[4], lv[4];
#pragma unroll
  for (int z = 0; z < 4; z++) {
    m[z]  = ml[(((size_t)z * 4 + h) * NN + q) * 2 + 0];
    lv[z] = ml[(((size_t)z * 4 + h) * NN + q) * 2 + 1];
  }
  const float ms = fmaxf(fmaxf(m[0], m[1]), fmaxf(m[2], m[3]));
  float w[4]; float ls = 0.f;
#pragma unroll
  for (int z = 0; z < 4; z++) {
    w[z] = exp2f(m[z] - ms);
    ls += lv[z] * w[z];
  }
  const float inv = 1.f / ls;
  float acc = 0.f;
#pragma unroll
  for (int z = 0; z < 4; z++)
    acc += bf2f(opart[((size_t)z * NN + q) * DM + t]) * w[z];
  ob[(size_t)q * DM + t] = f2bf(acc * inv);
}

// ---------------- LayerNorm over 256 (dual f32 + bf16 out) ------------------
__global__ __launch_bounds__(256) void ln_k(
    const float* __restrict__ x, const float* __restrict__ g,
    const float* __restrict__ b, float* __restrict__ y,
    unsigned short* __restrict__ yb) {
  __shared__ float bs[4], bs2[4];
  const int n = blockIdx.x, t = threadIdx.x;
  const float v = x[(size_t)n * DM + t];
  float s = v, s2 = v * v;
#pragma unroll
  for (int off = 32; off >= 1; off >>= 1) {
    s += __shfl_down(s, off, 64);
    s2 += __shfl_down(s2, off, 64);
  }
  const int wave = t >> 6, lane = t & 63;
  if (lane == 0) { bs[wave] = s; bs2[wave] = s2; }
  __syncthreads();
  const float ts = bs[0] + bs[1] + bs[2] + bs[3];
  const float ts2 = bs2[0] + bs2[1] + bs2[2] + bs2[3];
  const float mu = ts * (1.f / 256.f);
  const float var = ts2 * (1.f / 256.f) - mu * mu;
  const float rstd = 1.f / sqrtf(var + 1e-5f);
  const float o = (v - mu) * rstd * g[t] + b[t];
  y[(size_t)n * DM + t] = o;
  yb[(size_t)n * DM + t] = f2bf(o);
}

// ---------------- out = x^T ([4096,256] -> [256,4096]) ----------------------
__global__ __launch_bounds__(1024) void transpose_k(
    const float* __restrict__ x, float* __restrict__ out) {
  __shared__ float tile[32][33];
  const int n0 = blockIdx.x * 32, c0 = blockIdx.y * 32;
  const int tx = threadIdx.x, ty = threadIdx.y;
  tile[ty][tx] = x[(size_t)(n0 + ty) * DM + c0 + tx];
  __syncthreads();
  out[(size_t)(c0 + ty) * NN + n0 + tx] = tile[tx][ty];
}

// ---------------------------------------------------------------------------
extern "C" void kernel_launch(void* const* d_in, const int* in_sizes, int n_in,
                              void* d_out, int out_size, void* d_ws, size_t ws_size,
                              hipStream_t stream) {
  (void)in_sizes; (void)n_in; (void)out_size; (void)ws_size;
  const float* window   = (const float*)d_in[0];
  const float* gl_w     = (const float*)d_in[1];
  const float* gl_b     = (const float*)d_in[2];
  const float* enc_W    = (const float*)d_in[3];
  const float* enc_asrc = (const float*)d_in[4];
  const float* enc_adst = (const float*)d_in[5];
  const float* enc_b    = (const float*)d_in[6];
  const float* tr_wqkv  = (const float*)d_in[7];
  const float* tr_bqkv  = (const float*)d_in[8];
  const float* tr_wo    = (const float*)d_in[9];
  const float* tr_bo    = (const float*)d_in[10];
  const float* tr_ln1_g = (const float*)d_in[11];
  const float* tr_ln1_b = (const float*)d_in[12];
  const float* tr_w1    = (const float*)d_in[13];
  const float* tr_b1    = (const float*)d_in[14];
  const float* tr_w2    = (const float*)d_in[15];
  const float* tr_b2    = (const float*)d_in[16];
  const float* tr_ln2_g = (const float*)d_in[17];
  const float* tr_ln2_b = (const float*)d_in[18];
  const float* skip_w   = (const float*)d_in[19];
  const float* skip_b   = (const float*)d_in[20];
  const float* dec_W    = (const float*)d_in[21];
  const float* dec_asrc = (const float*)d_in[22];
  const float* dec_adst = (const float*)d_in[23];
  const float* dec_b    = (const float*)d_in[24];
  const float* dec_lW   = (const float*)d_in[25];
  const float* dec_lasrc= (const float*)d_in[26];
  const float* dec_ladst= (const float*)d_in[27];
  const float* dec_lb   = (const float*)d_in[28];
  float* outp = (float*)d_out;

  // ws layout (floats), end = 41.2 MB (< proven-safe 42.3 MB).
  float* ws   = (float*)d_ws;
  float* xa   = ws;                        // 1M
  float* xb   = ws + 1048576;              // 1M
  float* hp   = ws + 2097152;              // 1M; transformer: Kf+Vf fragments
  float* t1   = ws + 3145728;              // 1M (overlay: mlb)
  float* mlb  = t1;
  float* qkvb = ws + 4194304;              // 4096*768 bf16 ; sim: Aext
  float* Rg   = ws + 6291456;              // 2M: AwinExt | simc | opart | ffb
  float* simc = Rg;
  unsigned short* opartb = (unsigned short*)Rg;
  unsigned short* ffb    = (unsigned short*)Rg;
  float* es   = ws + 8388608;
  float* ed   = ws + 8404992;
  int*   idx  = (int*)(ws + 8421376);
  unsigned short* winb = (unsigned short*)(ws + 8486912);  // 1M bf16
  unsigned short* actb = (unsigned short*)(ws + 9011200);  // 1M bf16
  unsigned short* wb   = (unsigned short*)(ws + 9535488);  // weights bf16

  unsigned short* encWt = wb;
  unsigned short* wqkvb = wb + 196608;
  unsigned short* wob   = wb + 589824;
  unsigned short* w1t   = wb + 720896;
  unsigned short* w2t   = wb + 983040;
  unsigned short* skipt = wb + 1245184;
  unsigned short* dect  = wb + 1310720;
  unsigned short* declt = wb + 1441792;

  unsigned short* Aext = (unsigned short*)qkvb;            // sim A (split)
  unsigned short* Bext = (unsigned short*)xa;              // sim B (spans xa+xb)
  unsigned short* AwinExt = (unsigned short*)Rg;           // [Wh,Wl,Wh] (phase 1)
  unsigned short* BglExt  = actb;                          // [Gh,Gh,Gl] (phase 1)

  short* kfb = (short*)hp;                                 // 1M shorts (2 MB)
  short* vfb = (short*)hp + 1048576;                       // 1M shorts (2 MB)

  const dim3 B256(256);

  // 0) weight/activation bf16 prep
  {
    CastJob c0{window, winb, 262144};
    CastJob c1{tr_wqkv, wqkvb, 98304};
    CastJob c2{tr_wo, wob, 32768};
    castall_k<<<dim3(1024, 3), B256, 0, stream>>>(c0, c1, c2);
    TJobs tj;
    for (int i = 0; i < 3; i++) tj.j[i] = {enc_W + (size_t)i * 65536, encWt + (size_t)i * 65536, 256, 256};
    for (int i = 0; i < 2; i++) tj.j[3 + i] = {tr_w1 + (size_t)i * 131072, w1t + (size_t)i * 131072, 256, 512};
    for (int i = 0; i < 2; i++) tj.j[5 + i] = {tr_w2 + (size_t)i * 131072, w2t + (size_t)i * 131072, 512, 256};
    tj.j[7] = {skip_w, skipt, 256, 256};
    for (int i = 0; i < 2; i++) tj.j[8 + i] = {dec_W + (size_t)i * 65536, dect + (size_t)i * 65536, 256, 256};
    tj.j[10] = {dec_lW, declt, 256, 256};
    tcastall_k<<<dim3(16, 16, 11), B256, 0, stream>>>(tj);
  }

  // 1) h_gl = tanh(window@gl_w + gl_b) via split-precision MFMA, fused with
  //    the hi/lo split write for sim (Aext/Bext).
  wsplit_k<<<dim3(NN), B256, 0, stream>>>(window, AwinExt);
  gsplit_k<<<dim3(8, 8), B256, 0, stream>>>(gl_w, BglExt);
  mgemm_ts_k<<<dim3(4, 64), B256, 0, stream>>>(
      AwinExt, BglExt, gl_b, Aext, Bext, NN, DM, 768);

  // 2) sim via K=768 bf16 MFMA GEMM (64x128 tile) + top-16
  for (int c = 0; c < 8; c++) {
    mgemm2_k<<<dim3(32, 8), B256, 0, stream>>>(
        Aext + (size_t)c * 512 * 768, Bext, simc, 512, NN, 768);
    topk16_k<<<dim3(512), B256, 0, stream>>>(simc, idx, c * 512);
  }

  // 3) encoder: 3 GAT layers (H=4, relu)
  for (int i = 0; i < 3; i++) {
    const unsigned short* ain = (i == 0) ? winb : actb;
    mgemm_k<ACT_NONE, false, false, true, false><<<dim3(4, 64), B256, 0, stream>>>(
        ain, encWt + (size_t)i * 65536, nullptr, nullptr, hp, nullptr, NN, DM, DM);
    gat_prep_k<4><<<dim3(NN), B256, 0, stream>>>(hp, enc_asrc + i * 256, enc_adst + i * 256, es, ed);
    gat_aggr_k<4, true, true><<<dim3(NN), B256, 0, stream>>>(
        hp, es, ed, idx, enc_b + i * 256, xa, actb);
  }

  // 4) transformer x2
  for (int i = 0; i < 2; i++) {
    mgemm_k<ACT_NONE, true, false, false, true><<<dim3(12, 64), B256, 0, stream>>>(
        actb, wqkvb + (size_t)i * 196608, tr_bqkv + i * 768, nullptr,
        nullptr, (unsigned short*)qkvb, NN, 768, DM);
    kvfrag_k<<<dim3(128, 4), B256, 0, stream>>>((const short*)qkvb, kfb, vfb);
    attn_flash_k<<<dim3(NN / 128, 4, 4), B256, 0, stream>>>(
        (const short*)qkvb, kfb, vfb, opartb, mlb);
    attn_merge_k<<<dim3(NN), B256, 0, stream>>>(opartb, mlb, actb);
    mgemm_k<ACT_NONE, true, true, true, false><<<dim3(4, 64), B256, 0, stream>>>(
        actb, wob + (size_t)i * 65536, tr_bo + i * 256, xa, t1, nullptr, NN, DM, DM);
    ln_k<<<dim3(NN), B256, 0, stream>>>(t1, tr_ln1_g + i * 256, tr_ln1_b + i * 256, xb, actb);
    mgemm_k<ACT_RELU, true, false, false, true><<<dim3(8, 64), B256, 0, stream>>>(
        actb, w1t + (size_t)i * 131072, tr_b1 + i * 512, nullptr,
        nullptr, ffb, NN, 512, DM);
    mgemm_k<ACT_NONE, true, true, true, false><<<dim3(4, 64), B256, 0, stream>>>(
        ffb, w2t + (size_t)i * 131072, tr_b2 + i * 256, xb, t1, nullptr, NN, DM, 512);
    ln_k<<<dim3(NN), B256, 0, stream>>>(t1, tr_ln2_g + i * 256, tr_ln2_b + i * 256, xa, actb);
  }

  // 5) skip
  mgemm_k<ACT_NONE, true, true, false, true><<<dim3(4, 64), B256, 0, stream>>>(
      winb, skipt, skip_b, xa, nullptr, actb, NN, DM, DM);

  // 6) decoder: 2 GAT (H=4, relu) + final GAT (H=1)
  mgemm_k<ACT_NONE, false, false, true, false><<<dim3(4, 64), B256, 0, stream>>>(
      actb, dect, nullptr, nullptr, hp, nullptr, NN, DM, DM);
  gat_prep_k<4><<<dim3(NN), B256, 0, stream>>>(hp, dec_asrc, dec_adst, es, ed);
  gat_aggr_k<4, true, true><<<dim3(NN), B256, 0, stream>>>(hp, es, ed, idx, dec_b, xb, actb);

  mgemm_k<ACT_NONE, false, false, true, false><<<dim3(4, 64), B256, 0, stream>>>(
      actb, dect + 65536, nullptr, nullptr, hp, nullptr, NN, DM, DM);
  gat_prep_k<4><<<dim3(NN), B256, 0, stream>>>(hp, dec_asrc + 256, dec_adst + 256, es, ed);
  gat_aggr_k<4, true, true><<<dim3(NN), B256, 0, stream>>>(hp, es, ed, idx, dec_b + 256, xb, actb);

  mgemm_k<ACT_NONE, false, false, true, false><<<dim3(4, 64), B256, 0, stream>>>(
      actb, declt, nullptr, nullptr, hp, nullptr, NN, DM, DM);
  gat_prep_k<1><<<dim3(NN), B256, 0, stream>>>(hp, dec_lasrc, dec_ladst, es, ed);
  gat_aggr_k<1, false, false><<<dim3(NN), B256, 0, stream>>>(hp, es, ed, idx, dec_lb, xa, nullptr);

  // 7) out = xa^T
  transpose_k<<<dim3(NN / 32, DM / 32), dim3(32, 32), 0, stream>>>(xa, outp);
}

// Round 15
// 693.793 us; speedup vs baseline: 1.0253x; 1.0253x over previous
//
#include <hip/hip_runtime.h>
#include <math.h>

#define NN 4096
#define DM 256

enum { ACT_NONE = 0, ACT_RELU = 1, ACT_TANH = 2 };

typedef __attribute__((ext_vector_type(8))) short short8v;
typedef __attribute__((ext_vector_type(16))) float f32x16;

__device__ __forceinline__ unsigned short f2bf(float f) {
  unsigned int u = __float_as_uint(f);
  unsigned int r = (u + 0x7FFFu + ((u >> 16) & 1u)) >> 16;
  return (unsigned short)r;
}
__device__ __forceinline__ float bf2f(unsigned short u) {
  return __uint_as_float(((unsigned int)u) << 16);
}

// ---------------- batched weight prep ---------------------------------------
struct CastJob { const float* s; unsigned short* d; int n4; };
__global__ __launch_bounds__(256) void castall_k(CastJob j0, CastJob j1, CastJob j2) {
  const CastJob* jp = (blockIdx.y == 0) ? &j0 : (blockIdx.y == 1) ? &j1 : &j2;
  const int i = blockIdx.x * 256 + threadIdx.x;
  if (i < jp->n4) {
    const float4 v = ((const float4*)jp->s)[i];
    ushort4 u;
    u.x = f2bf(v.x); u.y = f2bf(v.y); u.z = f2bf(v.z); u.w = f2bf(v.w);
    ((ushort4*)jp->d)[i] = u;
  }
}

struct TJob { const float* s; unsigned short* d; int K; int N; };
struct TJobs { TJob j[11]; };
// src f32 [K][N] -> dst bf16 [N][K]
__global__ __launch_bounds__(256) void tcastall_k(TJobs js) {
  const TJob jb = js.j[blockIdx.z];
  const int n0 = blockIdx.x * 32, k0 = blockIdx.y * 32;
  if (n0 >= jb.N || k0 >= jb.K) return;
  __shared__ float tile[32][33];
  const int tx = threadIdx.x & 31, ty = threadIdx.x >> 5;
#pragma unroll
  for (int r2 = 0; r2 < 4; r2++)
    tile[ty + r2 * 8][tx] = jb.s[(size_t)(k0 + ty + r2 * 8) * jb.N + n0 + tx];
  __syncthreads();
#pragma unroll
  for (int r2 = 0; r2 < 4; r2++)
    jb.d[(size_t)(n0 + ty + r2 * 8) * jb.K + k0 + tx] = f2bf(tile[tx][ty + r2 * 8]);
}

// ---------------- split h into hi/lo bf16, build Aext/Bext for sim ----------
__global__ __launch_bounds__(256) void split_k(
    const float* __restrict__ h, unsigned short* __restrict__ Aext,
    unsigned short* __restrict__ Bext) {
  const int n = blockIdx.x, t = threadIdx.x;
  const float v = h[(size_t)n * DM + t];
  const unsigned short hi = f2bf(v);
  const unsigned short lo = f2bf(v - bf2f(hi));
  unsigned short* ar = Aext + (size_t)n * 768;
  unsigned short* br = Bext + (size_t)n * 768;
  ar[t] = hi; ar[256 + t] = lo; ar[512 + t] = hi;
  br[t] = hi; br[256 + t] = hi; br[512 + t] = lo;
}

// ---------------- f32 GEMM (graph-learning h_gl only) -----------------------
template<bool BT, int ACT, bool BIAS, bool RES>
__global__ __launch_bounds__(256) void gemm_k(
    const float* __restrict__ A, const float* __restrict__ B,
    const float* __restrict__ bias, const float* __restrict__ res,
    float* __restrict__ C, int M, int N, int K) {
  __shared__ float As[16][64];
  __shared__ float Bs[16][64];
  const int t = threadIdx.x;
  const int tx = t & 15, ty = t >> 4;
  const int m0 = blockIdx.y * 64, n0 = blockIdx.x * 64;
  float acc[4][4];
#pragma unroll
  for (int i = 0; i < 4; i++)
#pragma unroll
    for (int j = 0; j < 4; j++) acc[i][j] = 0.f;

  const int i_ld = t >> 2, kq = t & 3;
  for (int k0 = 0; k0 < K; k0 += 16) {
    float4 a4 = *(const float4*)(A + (size_t)(m0 + i_ld) * K + k0 + kq * 4);
    As[kq * 4 + 0][i_ld] = a4.x; As[kq * 4 + 1][i_ld] = a4.y;
    As[kq * 4 + 2][i_ld] = a4.z; As[kq * 4 + 3][i_ld] = a4.w;
    if (BT) {
      float4 b4 = *(const float4*)(B + (size_t)(n0 + i_ld) * K + k0 + kq * 4);
      Bs[kq * 4 + 0][i_ld] = b4.x; Bs[kq * 4 + 1][i_ld] = b4.y;
      Bs[kq * 4 + 2][i_ld] = b4.z; Bs[kq * 4 + 3][i_ld] = b4.w;
    } else {
      const int kk = t >> 4, j4 = (t & 15) * 4;
      float4 b4 = *(const float4*)(B + (size_t)(k0 + kk) * N + n0 + j4);
      *(float4*)&Bs[kk][j4] = b4;
    }
    __syncthreads();
#pragma unroll
    for (int kk = 0; kk < 16; kk++) {
      const float4 av = *(const float4*)&As[kk][ty * 4];
      const float4 bv = *(const float4*)&Bs[kk][tx * 4];
      acc[0][0] += av.x * bv.x; acc[0][1] += av.x * bv.y;
      acc[0][2] += av.x * bv.z; acc[0][3] += av.x * bv.w;
      acc[1][0] += av.y * bv.x; acc[1][1] += av.y * bv.y;
      acc[1][2] += av.y * bv.z; acc[1][3] += av.y * bv.w;
      acc[2][0] += av.z * bv.x; acc[2][1] += av.z * bv.y;
      acc[2][2] += av.z * bv.z; acc[2][3] += av.z * bv.w;
      acc[3][0] += av.w * bv.x; acc[3][1] += av.w * bv.y;
      acc[3][2] += av.w * bv.z; acc[3][3] += av.w * bv.w;
    }
    __syncthreads();
  }
  const int n = n0 + tx * 4;
#pragma unroll
  for (int i = 0; i < 4; i++) {
    const int m = m0 + ty * 4 + i;
    float4 v = make_float4(acc[i][0], acc[i][1], acc[i][2], acc[i][3]);
    if (BIAS) {
      v.x += bias[n + 0]; v.y += bias[n + 1];
      v.z += bias[n + 2]; v.w += bias[n + 3];
    }
    if (RES) {
      const float4 rv = *(const float4*)(res + (size_t)m * N + n);
      v.x += rv.x; v.y += rv.y; v.z += rv.z; v.w += rv.w;
    }
    if (ACT == ACT_RELU) {
      v.x = fmaxf(v.x, 0.f); v.y = fmaxf(v.y, 0.f);
      v.z = fmaxf(v.z, 0.f); v.w = fmaxf(v.w, 0.f);
    } else if (ACT == ACT_TANH) {
      v.x = tanhf(v.x); v.y = tanhf(v.y); v.z = tanhf(v.z); v.w = tanhf(v.w);
    }
    *(float4*)(C + (size_t)m * N + n) = v;
  }
}

// ---------------- bf16 MFMA GEMM: C = act(A@Bt^T (+bias) (+res)) ------------
// Staging via global_load_lds width=16: LDS dest linear, XOR swizzle applied
// on the GLOBAL source address; ds_read side reads chunk c at c^(r&7).
template<int ACT, bool BIAS, bool RES, bool F32OUT, bool B16OUT>
__global__ __launch_bounds__(256) void mgemm_k(
    const unsigned short* __restrict__ A, const unsigned short* __restrict__ Bt,
    const float* __restrict__ bias, const float* __restrict__ res,
    float* __restrict__ C, unsigned short* __restrict__ Cb,
    int M, int N, int K) {
  __shared__ short As[64][64];
  __shared__ short Bs[64][64];
  const int t = threadIdx.x;
  const int m0 = blockIdx.y * 64, n0 = blockIdx.x * 64;
  const int wid = t >> 6, l = t & 63, l31 = l & 31, g = l >> 5;
  const int wm = wid >> 1, wn = wid & 1;
  f32x16 acc;
#pragma unroll
  for (int r = 0; r < 16; r++) acc[r] = 0.f;

  const int r0 = wid * 16;
  const int lrow = l >> 3;
  const int pos = l & 7;
  const int swz = (pos ^ lrow) << 3;

  for (int k0 = 0; k0 < K; k0 += 64) {
#pragma unroll
    for (int j = 0; j < 2; j++) {
      const int row = r0 + j * 8 + lrow;
      const short* ga = (const short*)A + (size_t)(m0 + row) * K + k0 + swz;
      const short* gb = (const short*)Bt + (size_t)(n0 + row) * K + k0 + swz;
      __builtin_amdgcn_global_load_lds(
          (const __attribute__((address_space(1))) unsigned int*)ga,
          (__attribute__((address_space(3))) unsigned int*)&As[r0 + j * 8][0],
          16, 0, 0);
      __builtin_amdgcn_global_load_lds(
          (const __attribute__((address_space(1))) unsigned int*)gb,
          (__attribute__((address_space(3))) unsigned int*)&Bs[r0 + j * 8][0],
          16, 0, 0);
    }
    __syncthreads();
#pragma unroll
    for (int ck = 0; ck < 4; ck++) {
      const int c = ck * 2 + g;
      const short8v af = *(const short8v*)&As[wm * 32 + l31][(c ^ (l31 & 7)) * 8];
      const short8v bf = *(const short8v*)&Bs[wn * 32 + l31][(c ^ (l31 & 7)) * 8];
      acc = __builtin_amdgcn_mfma_f32_32x32x16_bf16(bf, af, acc, 0, 0, 0);
    }
    __syncthreads();
  }
  const int m = m0 + wm * 32 + l31;
#pragma unroll
  for (int b = 0; b < 4; b++) {
    const int n = n0 + wn * 32 + b * 8 + g * 4;
    float4 v = make_float4(acc[b * 4 + 0], acc[b * 4 + 1],
                           acc[b * 4 + 2], acc[b * 4 + 3]);
    if (BIAS) {
      v.x += bias[n + 0]; v.y += bias[n + 1];
      v.z += bias[n + 2]; v.w += bias[n + 3];
    }
    if (RES) {
      const float4 rv = *(const float4*)(res + (size_t)m * N + n);
      v.x += rv.x; v.y += rv.y; v.z += rv.z; v.w += rv.w;
    }
    if (ACT == ACT_RELU) {
      v.x = fmaxf(v.x, 0.f); v.y = fmaxf(v.y, 0.f);
      v.z = fmaxf(v.z, 0.f); v.w = fmaxf(v.w, 0.f);
    }
    if (F32OUT) *(float4*)(C + (size_t)m * N + n) = v;
    if (B16OUT) {
      ushort4 uv;
      uv.x = f2bf(v.x); uv.y = f2bf(v.y); uv.z = f2bf(v.z); uv.w = f2bf(v.w);
      *(ushort4*)(Cb + (size_t)m * N + n) = uv;
    }
  }
}

// ---------------- top-16: per-wave reg top16 + single-barrier merge ---------
__global__ __launch_bounds__(256) void topk16_k(
    const float* __restrict__ sim, int* __restrict__ idxo, int rowbase) {
  const int r = blockIdx.x, t = threadIdx.x;
  const int grow = rowbase + r;
  float val[16];
#pragma unroll
  for (int q = 0; q < 16; q++) {
    const int jj = q * 256 + t;
    float v = sim[(size_t)r * NN + jj];
    v = fmaxf(v, 0.f);
    if (jj == grow) v = -1.f;
    val[q] = v;
  }
  __shared__ float cv[64];
  __shared__ int cjs[64];
  const int wave = t >> 6, lane = t & 63;
  float myv = -3.f; int myj = 0;
  for (int it = 0; it < 16; it++) {
    float bv = -10.f; int bj = 0;
#pragma unroll
    for (int q = 0; q < 16; q++)
      if (val[q] > bv) { bv = val[q]; bj = q * 256 + t; }
#pragma unroll
    for (int off = 1; off < 64; off <<= 1) {
      const float ov = __shfl_xor(bv, off);
      const int oj = __shfl_xor(bj, off);
      if (ov > bv || (ov == bv && oj < bj)) { bv = ov; bj = oj; }
    }
    if (lane == it) { myv = bv; myj = bj; }
    if ((bj & 255) == t) {
      const int q = bj >> 8;
#pragma unroll
      for (int qq = 0; qq < 16; qq++) if (qq == q) val[qq] = -2.f;
    }
  }
  if (lane < 16) { cv[wave * 16 + lane] = myv; cjs[wave * 16 + lane] = myj; }
  __syncthreads();
  if (wave == 0) {
    float bv2 = cv[lane]; int bj2 = cjs[lane];
    for (int it = 0; it < 16; it++) {
      float wv = bv2; int wj = bj2;
#pragma unroll
      for (int off = 1; off < 64; off <<= 1) {
        const float ov = __shfl_xor(wv, off);
        const int oj = __shfl_xor(wj, off);
        if (ov > wv || (ov == wv && oj < wj)) { wv = ov; wj = oj; }
      }
      if (lane == 0) idxo[(size_t)grow * 16 + it] = wj;
      if (wj == bj2) bv2 = -3.f;
    }
  }
}

// ---------------- GAT: per-node attention-source/dest scalars ---------------
template<int H>
__global__ __launch_bounds__(256) void gat_prep_k(
    const float* __restrict__ h, const float* __restrict__ as,
    const float* __restrict__ ad, float* __restrict__ es, float* __restrict__ ed) {
  __shared__ float bs[4], bd[4];
  const int n = blockIdx.x, t = threadIdx.x;
  const float v = h[(size_t)n * DM + t];
  float ps = v * as[t];
  float pd = v * ad[t];
#pragma unroll
  for (int off = 32; off >= 1; off >>= 1) {
    ps += __shfl_down(ps, off, 64);
    pd += __shfl_down(pd, off, 64);
  }
  const int wave = t >> 6, lane = t & 63;
  if (H == 4) {
    if (lane == 0) { es[n * 4 + wave] = ps; ed[n * 4 + wave] = pd; }
  } else {
    if (lane == 0) { bs[wave] = ps; bd[wave] = pd; }
    __syncthreads();
    if (t == 0) {
      es[n] = bs[0] + bs[1] + bs[2] + bs[3];
      ed[n] = bd[0] + bd[1] + bd[2] + bd[3];
    }
  }
}

// ---------------- GAT: aggregate 17 in-edges --------------------------------
template<int H, bool RELU, bool B16OUT>
__global__ __launch_bounds__(256) void gat_aggr_k(
    const float* __restrict__ h, const float* __restrict__ es,
    const float* __restrict__ ed, const int* __restrict__ idx,
    const float* __restrict__ bias, float* __restrict__ out,
    unsigned short* __restrict__ outb) {
  const int j = blockIdx.x, t = threadIdx.x;
  const int hd = (H == 4) ? (t >> 6) : 0;
  __shared__ int srcs[17];
  if (t < 16) srcs[t] = idx[(size_t)j * 16 + t];
  if (t == 16) srcs[16] = j;
  __syncthreads();
  const float edj = ed[j * H + hd];
  float e[17]; float m = -1e30f;
#pragma unroll
  for (int k = 0; k < 17; k++) {
    float ev = es[srcs[k] * H + hd] + edj;
    ev = (ev >= 0.f) ? ev : 0.2f * ev;
    e[k] = ev; m = fmaxf(m, ev);
  }
  float s = 0.f;
#pragma unroll
  for (int k = 0; k < 17; k++) { e[k] = expf(e[k] - m); s += e[k]; }
  const float inv = 1.f / s;
  float acc = 0.f;
#pragma unroll
  for (int k = 0; k < 17; k++) acc += e[k] * h[(size_t)srcs[k] * DM + t];
  acc = acc * inv + bias[t];
  if (RELU) acc = fmaxf(acc, 0.f);
  out[(size_t)j * DM + t] = acc;
  if (B16OUT) outb[(size_t)j * DM + t] = f2bf(acc);
}

// ---------------- K/V fragment packer ---------------------------------------
__global__ __launch_bounds__(256) void kvfrag_k(
    const short* __restrict__ qkvs, short* __restrict__ kf,
    short* __restrict__ vf) {
  const int kc = blockIdx.x;   // 32-key chunk
  const int h = blockIdx.y;
  const int t = threadIdx.x;
  __shared__ short Ks[32][72];
  __shared__ short Vs[32][72];
  {
    const int row = t >> 3, ch = t & 7;
    const short* kp = qkvs + (size_t)(kc * 32 + row) * 768 + 256 + h * 64 + ch * 8;
    *(short8v*)&Ks[row][ch * 8] = *(const short8v*)kp;
    const short* vp = qkvs + (size_t)(kc * 32 + row) * 768 + 512 + h * 64 + ch * 8;
    *(short8v*)&Vs[row][ch * 8] = *(const short8v*)vp;
  }
  __syncthreads();
  {
    const int dc = t >> 6, l = t & 63, l31 = l & 31, g = l >> 5;
    short8v kv;
#pragma unroll
    for (int e = 0; e < 8; e++) kv[e] = Ks[l31][dc * 16 + g * 8 + e];
    *(short8v*)(kf + ((size_t)(h * 128 + kc) * 4 + dc) * 512 + l * 8) = kv;
  }
  {
    const int db = t >> 7, kg = (t >> 6) & 1, l = t & 63, l31 = l & 31, g = l >> 5;
    short8v vv;
#pragma unroll
    for (int e = 0; e < 8; e++) {
      const int j = kg * 16 + g * 8 + e;
      const int jp = (j & 19) | ((j & 4) << 1) | ((j & 8) >> 1);
      vv[e] = Vs[jp][db * 32 + l31];
    }
    *(short8v*)(vf + (((size_t)(h * 128 + kc) * 2 + db) * 2 + kg) * 512 + l * 8) = vv;
  }
}

// ---------------- bf16 MFMA flash attention: fragment-coalesced, z=4 --------
// 4 INDEPENDENT waves per 256-thread block (different q-tiles, no barriers).
#define LOADKV(KF, VF, KC) do {                                               \
    const short* kp_ = kfrag + ((size_t)(KC)) * 2048 + l * 8;                 \
    KF##0 = *(const short8v*)(kp_);                                           \
    KF##1 = *(const short8v*)(kp_ + 512);                                     \
    KF##2 = *(const short8v*)(kp_ + 1024);                                    \
    KF##3 = *(const short8v*)(kp_ + 1536);                                    \
    const short* vp_ = vfrag + ((size_t)(KC)) * 2048 + l * 8;                 \
    VF##0 = *(const short8v*)(vp_);                                           \
    VF##1 = *(const short8v*)(vp_ + 512);                                     \
    VF##2 = *(const short8v*)(vp_ + 1024);                                    \
    VF##3 = *(const short8v*)(vp_ + 1536);                                    \
  } while (0)

#define PROCESS(KF, VF) do {                                                  \
    f32x16 accS;                                                              \
    _Pragma("unroll") for (int r = 0; r < 16; r++) accS[r] = 0.f;             \
    __builtin_amdgcn_s_setprio(1);                                            \
    accS = __builtin_amdgcn_mfma_f32_32x32x16_bf16(KF##0, qf[0], accS, 0, 0, 0); \
    accS = __builtin_amdgcn_mfma_f32_32x32x16_bf16(KF##1, qf[1], accS, 0, 0, 0); \
    accS = __builtin_amdgcn_mfma_f32_32x32x16_bf16(KF##2, qf[2], accS, 0, 0, 0); \
    accS = __builtin_amdgcn_mfma_f32_32x32x16_bf16(KF##3, qf[3], accS, 0, 0, 0); \
    __builtin_amdgcn_s_setprio(0);                                            \
    float mt = -1e30f;                                                        \
    _Pragma("unroll") for (int r = 0; r < 16; r++) mt = fmaxf(mt, accS[r]);   \
    mt = fmaxf(mt, __shfl_xor(mt, 32));                                       \
    float pv[16]; float ls = 0.f;                                             \
    if (__all(mt <= mrun + 11.5416f)) {                                       \
      _Pragma("unroll") for (int r = 0; r < 16; r++) {                        \
        pv[r] = exp2f(accS[r] - mrun); ls += pv[r];                           \
      }                                                                       \
      ls += __shfl_xor(ls, 32); lrun += ls;                                   \
    } else {                                                                  \
      const float mnew = fmaxf(mrun, mt);                                     \
      const float corr = exp2f(mrun - mnew);                                  \
      _Pragma("unroll") for (int r = 0; r < 16; r++) {                        \
        pv[r] = exp2f(accS[r] - mnew); ls += pv[r];                           \
      }                                                                       \
      ls += __shfl_xor(ls, 32);                                               \
      lrun = lrun * corr + ls; mrun = mnew;                                   \
      _Pragma("unroll") for (int r = 0; r < 16; r++) {                        \
        accO[0][r] *= corr; accO[1][r] *= corr;                               \
      }                                                                       \
    }                                                                         \
    union { unsigned int u[8]; short8v s[2]; } pf;                            \
    _Pragma("unroll") for (int r = 0; r < 8; r++) {                           \
      unsigned int po;                                                        \
      asm("v_cvt_pk_bf16_f32 %0, %1, %2"                                      \
          : "=v"(po) : "v"(pv[2 * r]), "v"(pv[2 * r + 1]));                   \
      pf.u[r] = po;                                                           \
    }                                                                         \
    __builtin_amdgcn_s_setprio(1);                                            \
    accO[0] = __builtin_amdgcn_mfma_f32_32x32x16_bf16(VF##0, pf.s[0], accO[0], 0, 0, 0); \
    accO[0] = __builtin_amdgcn_mfma_f32_32x32x16_bf16(VF##1, pf.s[1], accO[0], 0, 0, 0); \
    accO[1] = __builtin_amdgcn_mfma_f32_32x32x16_bf16(VF##2, pf.s[0], accO[1], 0, 0, 0); \
    accO[1] = __builtin_amdgcn_mfma_f32_32x32x16_bf16(VF##3, pf.s[1], accO[1], 0, 0, 0); \
    __builtin_amdgcn_s_setprio(0);                                            \
  } while (0)

// grid (32 qgroups, 4 heads, 4 z), block = 256 (4 independent waves).
__global__ __launch_bounds__(256) void attn_flash_k(
    const short* __restrict__ qkvs, const short* __restrict__ kfb,
    const short* __restrict__ vfb, unsigned short* __restrict__ opart,
    float* __restrict__ ml) {
  const int t = threadIdx.x;
  const int wv = t >> 6;
  const int l = t & 63;
  const int qb = (blockIdx.x * 4 + wv) * 32;
  const int h = blockIdx.y;
  const int z = blockIdx.z;
  const int l31 = l & 31, g = l >> 5;

  short8v qf[4];
  {
    const short* qp = qkvs + (size_t)(qb + l31) * 768 + h * 64 + g * 8;
#pragma unroll
    for (int c = 0; c < 4; c++) {
      short8v qv = *(const short8v*)(qp + c * 16);
#pragma unroll
      for (int e = 0; e < 8; e++)
        qv[e] = (short)f2bf(bf2f((unsigned short)qv[e]) * 0.18033688f);
      qf[c] = qv;
    }
  }

  f32x16 accO[2];
#pragma unroll
  for (int r = 0; r < 16; r++) { accO[0][r] = 0.f; accO[1][r] = 0.f; }
  float mrun = -1e30f, lrun = 0.f;

  const short* kfrag = kfb + (size_t)h * 128 * 2048;
  const short* vfrag = vfb + (size_t)h * 128 * 2048;
  const int kc0 = z * 32;

  short8v kA0, kA1, kA2, kA3, vA0, vA1, vA2, vA3;
  short8v kB0, kB1, kB2, kB3, vB0, vB1, vB2, vB3;
  LOADKV(kA, vA, kc0);
  for (int it = 0; it < 16; it++) {
    LOADKV(kB, vB, kc0 + (it * 2 + 1));
    PROCESS(kA, vA);
    LOADKV(kA, vA, kc0 + ((it * 2 + 2) & 31));  // wraps on last iter
    PROCESS(kB, vB);
  }

  const int q = qb + l31;
  unsigned short* op = opart + ((size_t)z * NN + q) * DM + h * 64;
#pragma unroll
  for (int db = 0; db < 2; db++) {
#pragma unroll
    for (int rq = 0; rq < 4; rq++) {
      ushort4 v4;
      v4.x = f2bf(accO[db][rq * 4 + 0]);
      v4.y = f2bf(accO[db][rq * 4 + 1]);
      v4.z = f2bf(accO[db][rq * 4 + 2]);
      v4.w = f2bf(accO[db][rq * 4 + 3]);
      *(ushort4*)(op + db * 32 + rq * 8 + g * 4) = v4;
    }
  }
  if (g == 0) {
    ml[(((size_t)z * 4 + h) * NN + q) * 2 + 0] = mrun;   // log2-domain
    ml[(((size_t)z * 4 + h) * NN + q) * 2 + 1] = lrun;
  }
}

// ---------------- merge 4 flash partials (m in log2 domain) -----------------
__global__ __launch_bounds__(256) void attn_merge_k(
    const unsigned short* __restrict__ opart, const float* __restrict__ ml,
    unsigned short* __restrict__ ob) {
  const int q = blockIdx.x;
  const int t = threadIdx.x;
  const int h = t >> 6;
  float m[4], lv[4];
#pragma unroll
  for (int z = 0; z < 4; z++) {
    m[z]  = ml[(((size_t)z * 4 + h) * NN + q) * 2 + 0];
    lv[z] = ml[(((size_t)z * 4 + h) * NN + q) * 2 + 1];
  }
  const float ms = fmaxf(fmaxf(m[0], m[1]), fmaxf(m[2], m[3]));
  float w[4]; float ls = 0.f;
#pragma unroll
  for (int z = 0; z < 4; z++) {
    w[z] = exp2f(m[z] - ms);
    ls += lv[z] * w[z];
  }
  const float inv = 1.f / ls;
  float acc = 0.f;
#pragma unroll
  for (int z = 0; z < 4; z++)
    acc += bf2f(opart[((size_t)z * NN + q) * DM + t]) * w[z];
  ob[(size_t)q * DM + t] = f2bf(acc * inv);
}

// ---------------- LayerNorm over 256 (dual f32 + bf16 out) ------------------
__global__ __launch_bounds__(256) void ln_k(
    const float* __restrict__ x, const float* __restrict__ g,
    const float* __restrict__ b, float* __restrict__ y,
    unsigned short* __restrict__ yb) {
  __shared__ float bs[4], bs2[4];
  const int n = blockIdx.x, t = threadIdx.x;
  const float v = x[(size_t)n * DM + t];
  float s = v, s2 = v * v;
#pragma unroll
  for (int off = 32; off >= 1; off >>= 1) {
    s += __shfl_down(s, off, 64);
    s2 += __shfl_down(s2, off, 64);
  }
  const int wave = t >> 6, lane = t & 63;
  if (lane == 0) { bs[wave] = s; bs2[wave] = s2; }
  __syncthreads();
  const float ts = bs[0] + bs[1] + bs[2] + bs[3];
  const float ts2 = bs2[0] + bs2[1] + bs2[2] + bs2[3];
  const float mu = ts * (1.f / 256.f);
  const float var = ts2 * (1.f / 256.f) - mu * mu;
  const float rstd = 1.f / sqrtf(var + 1e-5f);
  const float o = (v - mu) * rstd * g[t] + b[t];
  y[(size_t)n * DM + t] = o;
  yb[(size_t)n * DM + t] = f2bf(o);
}

// ---------------- out = x^T ([4096,256] -> [256,4096]) ----------------------
__global__ __launch_bounds__(1024) void transpose_k(
    const float* __restrict__ x, float* __restrict__ out) {
  __shared__ float tile[32][33];
  const int n0 = blockIdx.x * 32, c0 = blockIdx.y * 32;
  const int tx = threadIdx.x, ty = threadIdx.y;
  tile[ty][tx] = x[(size_t)(n0 + ty) * DM + c0 + tx];
  __syncthreads();
  out[(size_t)(c0 + ty) * NN + n0 + tx] = tile[tx][ty];
}

// ---------------------------------------------------------------------------
extern "C" void kernel_launch(void* const* d_in, const int* in_sizes, int n_in,
                              void* d_out, int out_size, void* d_ws, size_t ws_size,
                              hipStream_t stream) {
  (void)in_sizes; (void)n_in; (void)out_size; (void)ws_size;
  const float* window   = (const float*)d_in[0];
  const float* gl_w     = (const float*)d_in[1];
  const float* gl_b     = (const float*)d_in[2];
  const float* enc_W    = (const float*)d_in[3];
  const float* enc_asrc = (const float*)d_in[4];
  const float* enc_adst = (const float*)d_in[5];
  const float* enc_b    = (const float*)d_in[6];
  const float* tr_wqkv  = (const float*)d_in[7];
  const float* tr_bqkv  = (const float*)d_in[8];
  const float* tr_wo    = (const float*)d_in[9];
  const float* tr_bo    = (const float*)d_in[10];
  const float* tr_ln1_g = (const float*)d_in[11];
  const float* tr_ln1_b = (const float*)d_in[12];
  const float* tr_w1    = (const float*)d_in[13];
  const float* tr_b1    = (const float*)d_in[14];
  const float* tr_w2    = (const float*)d_in[15];
  const float* tr_b2    = (const float*)d_in[16];
  const float* tr_ln2_g = (const float*)d_in[17];
  const float* tr_ln2_b = (const float*)d_in[18];
  const float* skip_w   = (const float*)d_in[19];
  const float* skip_b   = (const float*)d_in[20];
  const float* dec_W    = (const float*)d_in[21];
  const float* dec_asrc = (const float*)d_in[22];
  const float* dec_adst = (const float*)d_in[23];
  const float* dec_b    = (const float*)d_in[24];
  const float* dec_lW   = (const float*)d_in[25];
  const float* dec_lasrc= (const float*)d_in[26];
  const float* dec_ladst= (const float*)d_in[27];
  const float* dec_lb   = (const float*)d_in[28];
  float* outp = (float*)d_out;

  // ws layout (floats), end = 41.2 MB (< proven-safe 42.3 MB).
  float* ws   = (float*)d_ws;
  float* xa   = ws;                        // 1M
  float* xb   = ws + 1048576;              // 1M
  float* hp   = ws + 2097152;              // 1M; transformer: Kf+Vf fragments
  float* t1   = ws + 3145728;              // 1M (overlays: hgl, mlb)
  float* hgl  = t1;
  float* mlb  = t1;
  float* qkvb = ws + 4194304;              // 4096*768 bf16 ; sim: Aext
  float* Rg   = ws + 6291456;              // 2M: simc | opart | ffb
  float* simc = Rg;
  unsigned short* opartb = (unsigned short*)Rg;
  unsigned short* ffb    = (unsigned short*)Rg;
  float* es   = ws + 8388608;
  float* ed   = ws + 8404992;
  int*   idx  = (int*)(ws + 8421376);
  unsigned short* winb = (unsigned short*)(ws + 8486912);  // 1M bf16
  unsigned short* actb = (unsigned short*)(ws + 9011200);  // 1M bf16
  unsigned short* wb   = (unsigned short*)(ws + 9535488);  // weights bf16

  unsigned short* encWt = wb;
  unsigned short* wqkvb = wb + 196608;
  unsigned short* wob   = wb + 589824;
  unsigned short* w1t   = wb + 720896;
  unsigned short* w2t   = wb + 983040;
  unsigned short* skipt = wb + 1245184;
  unsigned short* dect  = wb + 1310720;
  unsigned short* declt = wb + 1441792;

  unsigned short* Aext = (unsigned short*)qkvb;
  unsigned short* Bext = (unsigned short*)xa;              // spans xa+xb

  short* kfb = (short*)hp;                                 // 1M shorts (2 MB)
  short* vfb = (short*)hp + 1048576;                       // 1M shorts (2 MB)

  const dim3 B256(256);

  // 0) weight/activation bf16 prep (2 launches)
  {
    CastJob c0{window, winb, 262144};
    CastJob c1{tr_wqkv, wqkvb, 98304};
    CastJob c2{tr_wo, wob, 32768};
    castall_k<<<dim3(1024, 3), B256, 0, stream>>>(c0, c1, c2);
    TJobs tj;
    for (int i = 0; i < 3; i++) tj.j[i] = {enc_W + (size_t)i * 65536, encWt + (size_t)i * 65536, 256, 256};
    for (int i = 0; i < 2; i++) tj.j[3 + i] = {tr_w1 + (size_t)i * 131072, w1t + (size_t)i * 131072, 256, 512};
    for (int i = 0; i < 2; i++) tj.j[5 + i] = {tr_w2 + (size_t)i * 131072, w2t + (size_t)i * 131072, 512, 256};
    tj.j[7] = {skip_w, skipt, 256, 256};
    for (int i = 0; i < 2; i++) tj.j[8 + i] = {dec_W + (size_t)i * 65536, dect + (size_t)i * 65536, 256, 256};
    tj.j[10] = {dec_lW, declt, 256, 256};
    tcastall_k<<<dim3(16, 16, 11), B256, 0, stream>>>(tj);
  }

  // 1) h_gl = tanh(window @ gl_w + gl_b)   [f32: graph topology]
  gemm_k<false, ACT_TANH, true, false><<<dim3(DM / 64, NN / 64), B256, 0, stream>>>(
      window, gl_w, gl_b, nullptr, hgl, NN, DM, DM);

  // 2) sim via split-precision K=768 bf16 MFMA GEMM + top-16
  split_k<<<dim3(NN), B256, 0, stream>>>(hgl, Aext, Bext);
  for (int c = 0; c < 8; c++) {
    mgemm_k<ACT_NONE, false, false, true, false><<<dim3(64, 8), B256, 0, stream>>>(
        Aext + (size_t)c * 512 * 768, Bext, nullptr, nullptr, simc, nullptr,
        512, NN, 768);
    topk16_k<<<dim3(512), B256, 0, stream>>>(simc, idx, c * 512);
  }

  // 3) encoder: 3 GAT layers (H=4, relu)
  for (int i = 0; i < 3; i++) {
    const unsigned short* ain = (i == 0) ? winb : actb;
    mgemm_k<ACT_NONE, false, false, true, false><<<dim3(4, 64), B256, 0, stream>>>(
        ain, encWt + (size_t)i * 65536, nullptr, nullptr, hp, nullptr, NN, DM, DM);
    gat_prep_k<4><<<dim3(NN), B256, 0, stream>>>(hp, enc_asrc + i * 256, enc_adst + i * 256, es, ed);
    gat_aggr_k<4, true, true><<<dim3(NN), B256, 0, stream>>>(
        hp, es, ed, idx, enc_b + i * 256, xa, actb);
  }

  // 4) transformer x2
  for (int i = 0; i < 2; i++) {
    mgemm_k<ACT_NONE, true, false, false, true><<<dim3(12, 64), B256, 0, stream>>>(
        actb, wqkvb + (size_t)i * 196608, tr_bqkv + i * 768, nullptr,
        nullptr, (unsigned short*)qkvb, NN, 768, DM);
    kvfrag_k<<<dim3(128, 4), B256, 0, stream>>>((const short*)qkvb, kfb, vfb);
    attn_flash_k<<<dim3(NN / 128, 4, 4), B256, 0, stream>>>(
        (const short*)qkvb, kfb, vfb, opartb, mlb);
    attn_merge_k<<<dim3(NN), B256, 0, stream>>>(opartb, mlb, actb);
    mgemm_k<ACT_NONE, true, true, true, false><<<dim3(4, 64), B256, 0, stream>>>(
        actb, wob + (size_t)i * 65536, tr_bo + i * 256, xa, t1, nullptr, NN, DM, DM);
    ln_k<<<dim3(NN), B256, 0, stream>>>(t1, tr_ln1_g + i * 256, tr_ln1_b + i * 256, xb, actb);
    mgemm_k<ACT_RELU, true, false, false, true><<<dim3(8, 64), B256, 0, stream>>>(
        actb, w1t + (size_t)i * 131072, tr_b1 + i * 512, nullptr,
        nullptr, ffb, NN, 512, DM);
    mgemm_k<ACT_NONE, true, true, true, false><<<dim3(4, 64), B256, 0, stream>>>(
        ffb, w2t + (size_t)i * 131072, tr_b2 + i * 256, xb, t1, nullptr, NN, DM, 512);
    ln_k<<<dim3(NN), B256, 0, stream>>>(t1, tr_ln2_g + i * 256, tr_ln2_b + i * 256, xa, actb);
  }

  // 5) skip
  mgemm_k<ACT_NONE, true, true, false, true><<<dim3(4, 64), B256, 0, stream>>>(
      winb, skipt, skip_b, xa, nullptr, actb, NN, DM, DM);

  // 6) decoder: 2 GAT (H=4, relu) + final GAT (H=1)
  mgemm_k<ACT_NONE, false, false, true, false><<<dim3(4, 64), B256, 0, stream>>>(
      actb, dect, nullptr, nullptr, hp, nullptr, NN, DM, DM);
  gat_prep_k<4><<<dim3(NN), B256, 0, stream>>>(hp, dec_asrc, dec_adst, es, ed);
  gat_aggr_k<4, true, true><<<dim3(NN), B256, 0, stream>>>(hp, es, ed, idx, dec_b, xb, actb);

  mgemm_k<ACT_NONE, false, false, true, false><<<dim3(4, 64), B256, 0, stream>>>(
      actb, dect + 65536, nullptr, nullptr, hp, nullptr, NN, DM, DM);
  gat_prep_k<4><<<dim3(NN), B256, 0, stream>>>(hp, dec_asrc + 256, dec_adst + 256, es, ed);
  gat_aggr_k<4, true, true><<<dim3(NN), B256, 0, stream>>>(hp, es, ed, idx, dec_b + 256, xb, actb);

  mgemm_k<ACT_NONE, false, false, true, false><<<dim3(4, 64), B256, 0, stream>>>(
      actb, declt, nullptr, nullptr, hp, nullptr, NN, DM, DM);
  gat_prep_k<1><<<dim3(NN), B256, 0, stream>>>(hp, dec_lasrc, dec_ladst, es, ed);
  gat_aggr_k<1, false, false><<<dim3(NN), B256, 0, stream>>>(hp, es, ed, idx, dec_lb, xa, nullptr);

  // 7) out = xa^T
  transpose_k<<<dim3(NN / 32, DM / 32), dim3(32, 32), 0, stream>>>(xa, outp);
}